// Round 1
// baseline (147.155 us; speedup 1.0000x reference)
//
#include <hip/hip_runtime.h>

// Problem constants (fixed by the reference):
//   T = B*C = 4 trees, N = 262144 = 2^18 nodes/tree, HW = 1048576 = 2^20 pixels/tree
#define NT 4
#define NN 262144
#define NMASK (NN - 1)
#define HW 1048576

// ---------------------------------------------------------------------------
// K1: build packed node records {parent, c} where
//   c[i] = sigmoid(clip(1000*(attr[i]-thr), -12, 12)) * (levels[i]-levels[parent[i]])
//   c[root]=levels[root], parent[root]=0
// One 8B record per node -> each walk step in K2 is a single dwordx2 gather.
// ---------------------------------------------------------------------------
__global__ __launch_bounds__(256) void k_build(const float* __restrict__ attr,
                                               const float* __restrict__ levels,
                                               const float* __restrict__ thr,
                                               const int* __restrict__ parent,
                                               int2* __restrict__ cmb) {
    int i = blockIdx.x * 256 + threadIdx.x;      // 0 .. NT*NN-1
    int n = i & NMASK;                           // node within tree
    int tbase = i ^ n;                           // tree base index
    int p = parent[i] & NMASK;                   // parent (mask = OOB guard)
    float lv = levels[i];
    float lp = levels[tbase | p];                // random gather, L2-resident (1MB/tree)
    float z = 1000.0f * (attr[i] - thr[0]);
    z = fminf(fmaxf(z, -12.0f), 12.0f);
    float s = 1.0f / (1.0f + __expf(-z));
    float c = s * (lv - lp);
    if (n == 0) { c = lv; p = 0; }               // root: c = levels[0], self-parent
    int2 o;
    o.x = p;
    o.y = __float_as_int(c);
    cmb[i] = o;
}

// ---------------------------------------------------------------------------
// K2: per-node chain walk to root. v[i] = sum of c along path i -> root.
// parent[i] < i and depth ~ ln(N) (~12 avg, ~34 max for a random recursive
// tree), so walking beats pointer-doubling by ~landing all work in one pass.
// 4 independent chains per thread for memory-level parallelism; finished
// chains keep loading node 0 (coalesced broadcast) with zero weight instead
// of diverging.
// ---------------------------------------------------------------------------
__global__ __launch_bounds__(256) void k_walk(const int2* __restrict__ cmb,
                                              float* __restrict__ v) {
    int b = blockIdx.x * 1024;                   // block handles 1024 contiguous nodes
    int tbase = b & ~NMASK;                      // whole block is inside one tree
    const int2* ctree = cmb + tbase;

    int   cur[4];
    float acc[4];
#pragma unroll
    for (int k = 0; k < 4; ++k) {
        cur[k] = (b - tbase) + threadIdx.x + k * 256;
        acc[k] = 0.0f;
    }

    int alive = 0xF;
    // depth+1 iterations needed; max depth ~34 << 64 (cap doubles as a
    // hang-guard if capture ever runs on poisoned inputs).
    for (int it = 0; it < 64 && alive; ++it) {
#pragma unroll
        for (int k = 0; k < 4; ++k) {
            int c_ = cur[k];
            int2 pc = ctree[c_];                 // single 8B gather per step
            float w = (alive >> k) & 1 ? 1.0f : 0.0f;
            acc[k] += w * __int_as_float(pc.y);
            if (c_ == 0) alive &= ~(1 << k);
            cur[k] = (c_ == 0) ? 0 : (pc.x & NMASK);
        }
    }

#pragma unroll
    for (int k = 0; k < 4; ++k)
        v[b + threadIdx.x + k * 256] = acc[k];   // coalesced
}

// ---------------------------------------------------------------------------
// K3: pixel gather  y[t][p] = v[t][pixel_to_node[t][p]], int4/float4 vectorized.
// ---------------------------------------------------------------------------
__global__ __launch_bounds__(256) void k_pix(const float* __restrict__ v,
                                             const int* __restrict__ p2n,
                                             float* __restrict__ y) {
    int i = blockIdx.x * 256 + threadIdx.x;      // handles 4 pixels
    int4 idx = ((const int4*)p2n)[i];
    int pix0 = i << 2;
    int t = pix0 >> 20;                          // HW = 2^20, 4 pixels share a tree
    const float* vt = v + (t << 18);
    float4 o;
    o.x = vt[idx.x & NMASK];
    o.y = vt[idx.y & NMASK];
    o.z = vt[idx.z & NMASK];
    o.w = vt[idx.w & NMASK];
    ((float4*)y)[i] = o;
}

extern "C" void kernel_launch(void* const* d_in, const int* in_sizes, int n_in,
                              void* d_out, int out_size, void* d_ws, size_t ws_size,
                              hipStream_t stream) {
    // setup_inputs order: 0:x (unused), 1:attr_norm, 2:levels, 3:thr, 4:parent, 5:pixel_to_node
    const float* attr   = (const float*)d_in[1];
    const float* levels = (const float*)d_in[2];
    const float* thr    = (const float*)d_in[3];
    const int*   parent = (const int*)d_in[4];
    const int*   p2n    = (const int*)d_in[5];
    float*       y      = (float*)d_out;

    // workspace: cmb = NT*NN int2 (8 MB), v = NT*NN float (4 MB)
    int2*  cmb = (int2*)d_ws;
    float* v   = (float*)((char*)d_ws + (size_t)NT * NN * sizeof(int2));

    k_build<<<NT * NN / 256, 256, 0, stream>>>(attr, levels, thr, parent, cmb);
    k_walk <<<NT * NN / 1024, 256, 0, stream>>>(cmb, v);
    k_pix  <<<NT * HW / 4 / 256, 256, 0, stream>>>(v, p2n, y);
}

// Round 2
// 135.493 us; speedup vs baseline: 1.0861x; 1.0861x over previous
//
#include <hip/hip_runtime.h>

// Problem constants (fixed by the reference):
//   T = B*C = 4 trees, N = 262144 = 2^18 nodes/tree, HW = 1048576 = 2^20 pixels/tree
#define NT 4
#define NN 262144
#define NMASK (NN - 1)
#define HW 1048576
#define KPRE 16384   // prefix cutoff: v[0..KPRE) precomputed, main walk stops below it

// XCD-locality swizzle: blocks are dispatched round-robin across 8 XCDs
// (heuristic, perf-only). Map tree = (b&7)>>1 so each XCD touches exactly one
// tree's arrays (2MB cmb + 1MB v), which fits its 4MB L2.
#define SWIZ(b, tree, chunk)                \
    int tree  = ((b) & 7) >> 1;             \
    int chunk = (((b) >> 3) << 1) | ((b) & 1);

// ---------------------------------------------------------------------------
// K1: build packed node records {parent, c} where
//   c[i] = sigmoid(clip(1000*(attr[i]-thr), -12, 12)) * (levels[i]-levels[parent[i]])
//   c[root]=levels[root], parent[root]=0
// One 8B record per node -> each walk step is a single dwordx2 gather.
// ---------------------------------------------------------------------------
__global__ __launch_bounds__(256) void k_build(const float* __restrict__ attr,
                                               const float* __restrict__ levels,
                                               const float* __restrict__ thr,
                                               const int* __restrict__ parent,
                                               int2* __restrict__ cmb) {
    SWIZ(blockIdx.x, tree, chunk)            // 4096 blocks, 1024 chunks/tree
    int n = chunk * 256 + threadIdx.x;       // node within tree
    int i = (tree << 18) + n;
    int p = parent[i] & NMASK;               // parent (mask = OOB guard)
    float lv = levels[i];
    float lp = levels[(tree << 18) | p];     // random gather, tree-local (L2)
    float z = 1000.0f * (attr[i] - thr[0]);
    z = fminf(fmaxf(z, -12.0f), 12.0f);
    float s = 1.0f / (1.0f + __expf(-z));
    float c = s * (lv - lp);
    if (n == 0) { c = lv; p = 0; }           // root: c = levels[0], self-parent
    cmb[i] = make_int2(p, __float_as_int(c));
}

// ---------------------------------------------------------------------------
// K2: prefix solve. v[i] for i < KPRE by walking to root (all ancestors of a
// node are below it, so chains stay inside the first KPRE records = 128KB/tree,
// L2-resident). Avg depth ~ln(KPRE)=9.7, max ~28.
// ---------------------------------------------------------------------------
__global__ __launch_bounds__(256) void k_prefix(const int2* __restrict__ cmb,
                                                float* __restrict__ v) {
    SWIZ(blockIdx.x, tree, chunk)            // 256 blocks, 64 chunks/tree
    int node = chunk * 256 + threadIdx.x;    // 0..KPRE-1
    const int2* ctree = cmb + (tree << 18);
    float acc = 0.0f;
    int cur = node;
    bool alive = true;
    for (int it = 0; it < 64 && __any(alive); ++it) {
        if (alive) {
            int2 rec = ctree[cur];
            acc += __int_as_float(rec.y);    // includes levels[0] at the root
            if (cur == 0) alive = false;
            else cur = rec.x;                // rec.x < cur < KPRE
        }
    }
    v[(tree << 18) + node] = acc;
}

// ---------------------------------------------------------------------------
// K3: main walk for nodes >= KPRE. Chain walks until it drops below KPRE,
// then adds the precomputed prefix value. Expected steps ln(NN/KPRE) ~= 2.8
// (vs 12.5 to the root), so gather count drops ~4.5x. 4 chains/thread for MLP.
// ---------------------------------------------------------------------------
__global__ __launch_bounds__(256) void k_walk(const int2* __restrict__ cmb,
                                              float* __restrict__ v) {
    SWIZ(blockIdx.x, tree, chunk)            // 960 blocks, 240 chunks/tree
    int base = KPRE + chunk * 1024;          // node offset within tree
    const int2*  ctree = cmb + (tree << 18);
    const float* vtree = v + (tree << 18);

    int   cur[4];
    float acc[4];
    int alive = 0xF;
#pragma unroll
    for (int k = 0; k < 4; ++k) {
        cur[k] = base + threadIdx.x + k * 256;
        acc[k] = 0.0f;
    }
    // max steps-to-KPRE over a block's 1024 chains ~12; cap 64 is a hang-guard.
    for (int it = 0; it < 64 && __any(alive); ++it) {
#pragma unroll
        for (int k = 0; k < 4; ++k) {
            if (alive & (1 << k)) {
                int2 rec = ctree[cur[k]];    // one 8B gather per step, L2-hit
                acc[k] += __int_as_float(rec.y);
                int nxt = rec.x;
                if (nxt < KPRE) {            // terminate: fold in prefix value
                    acc[k] += vtree[nxt];    // 64KB/tree -> L1/L2-hit
                    alive &= ~(1 << k);
                } else {
                    cur[k] = nxt;
                }
            }
        }
    }
#pragma unroll
    for (int k = 0; k < 4; ++k)
        v[(tree << 18) + base + threadIdx.x + k * 256] = acc[k];  // coalesced
}

// ---------------------------------------------------------------------------
// K4: pixel gather  y[t][p] = v[t][pixel_to_node[t][p]], int4/float4 vectorized.
// Swizzled so each XCD gathers from one tree's 1MB v array.
// ---------------------------------------------------------------------------
__global__ __launch_bounds__(256) void k_pix(const float* __restrict__ v,
                                             const int* __restrict__ p2n,
                                             float* __restrict__ y) {
    SWIZ(blockIdx.x, tree, chunk)            // 4096 blocks, 1024 chunks/tree
    int i = (tree << 18) + chunk * 256 + threadIdx.x;  // int4 index
    int4 idx = ((const int4*)p2n)[i];
    const float* vt = v + (tree << 18);
    float4 o;
    o.x = vt[idx.x & NMASK];
    o.y = vt[idx.y & NMASK];
    o.z = vt[idx.z & NMASK];
    o.w = vt[idx.w & NMASK];
    ((float4*)y)[i] = o;
}

extern "C" void kernel_launch(void* const* d_in, const int* in_sizes, int n_in,
                              void* d_out, int out_size, void* d_ws, size_t ws_size,
                              hipStream_t stream) {
    // setup_inputs order: 0:x (unused), 1:attr_norm, 2:levels, 3:thr, 4:parent, 5:pixel_to_node
    const float* attr   = (const float*)d_in[1];
    const float* levels = (const float*)d_in[2];
    const float* thr    = (const float*)d_in[3];
    const int*   parent = (const int*)d_in[4];
    const int*   p2n    = (const int*)d_in[5];
    float*       y      = (float*)d_out;

    // workspace: cmb = NT*NN int2 (8 MB), v = NT*NN float (4 MB)
    int2*  cmb = (int2*)d_ws;
    float* v   = (float*)((char*)d_ws + (size_t)NT * NN * sizeof(int2));

    k_build <<<NT * NN / 256, 256, 0, stream>>>(attr, levels, thr, parent, cmb);
    k_prefix<<<NT * KPRE / 256, 256, 0, stream>>>(cmb, v);
    k_walk  <<<NT * (NN - KPRE) / 1024, 256, 0, stream>>>(cmb, v);
    k_pix   <<<NT * HW / 4 / 256, 256, 0, stream>>>(v, p2n, y);
}